// Round 2
// baseline (676.088 us; speedup 1.0000x reference)
//
#include <hip/hip_runtime.h>
#include <math.h>

#define M_ROWS 100000
#define PITCH  264        // 256 + 8 bf16 pad: row stride 528B; measured 0 bank conflicts

typedef __attribute__((ext_vector_type(8)))  short  short8;
typedef __attribute__((ext_vector_type(16))) float  float16v;

__device__ __forceinline__ unsigned short bf16_rne(float f) {
    unsigned u = __builtin_bit_cast(unsigned, f);
    u += 0x7FFFu + ((u >> 16) & 1u);
    return (unsigned short)(u >> 16);
}

__device__ __forceinline__ float sigmoid_fast(float x) {
    return 1.0f / (1.0f + __expf(-x));
}
__device__ __forceinline__ float tanh_fast(float x) {
    return 1.0f - 2.0f / (__expf(2.0f * x) + 1.0f);   // correct limits at +/-inf
}

// ---------------------------------------------------------------------------
// prep: swizzle weights f32 -> bf16 into MFMA B-fragment order, build mask,
// init ordered-uint max accumulator.
//
// Swizzled layout (short8 "chunk" units): chunk c = ((g*16 + kc)*6 + s)*64 + lane
//   g  = 32-column group (0..7), jj = g*32 + (lane&31)
//   s  = gate slab 0..2 = ih r/z/n, 3..5 = hh r/z/n
//   kc = K-step (0..15), lane consumes k = kc*16 + (lane>>5)*8 + j
// In the main loop a wave reads chunk base + lane -> fully coalesced 1KB/instr,
// sequential 96KB stream per jt-tile; whole table (786KB) is L2-resident.
// ---------------------------------------------------------------------------
#define NCHUNK 49152      // 8*16*6*64

__global__ void prep_kernel(const float* __restrict__ wih,
                            const float* __restrict__ whh,
                            const int* __restrict__ divided,
                            unsigned short* __restrict__ wswz,
                            unsigned int* __restrict__ maxacc,
                            int* __restrict__ maskbuf)
{
    int idx = blockIdx.x * 256 + threadIdx.x;
    if (idx < NCHUNK) {
        int lane = idx & 63;
        int t    = idx >> 6;          // 0..767
        int s    = t % 6;
        int t2   = t / 6;             // 0..127
        int kc   = t2 & 15;
        int g    = t2 >> 4;           // 0..7
        int row  = (s % 3) * 256 + g * 32 + (lane & 31);
        int col  = kc * 16 + (lane >> 5) * 8;
        const float* src = (s < 3 ? wih : whh) + row * 256 + col;
        float4 a = reinterpret_cast<const float4*>(src)[0];
        float4 b = reinterpret_cast<const float4*>(src)[1];
        uint4 p;
        p.x = (unsigned)bf16_rne(a.x) | ((unsigned)bf16_rne(a.y) << 16);
        p.y = (unsigned)bf16_rne(a.z) | ((unsigned)bf16_rne(a.w) << 16);
        p.z = (unsigned)bf16_rne(b.x) | ((unsigned)bf16_rne(b.y) << 16);
        p.w = (unsigned)bf16_rne(b.z) | ((unsigned)bf16_rne(b.w) << 16);
        reinterpret_cast<uint4*>(wswz)[idx] = p;
    } else if (idx < NCHUNK + M_ROWS) {
        int m = idx - NCHUNK;
        maskbuf[m] = (divided[3 * m] > 0) | (divided[3 * m + 1] > 0) | (divided[3 * m + 2] > 0);
    } else if (idx < NCHUNK + M_ROWS + 256) {
        maxacc[idx - NCHUNK - M_ROWS] = 0u;    // below ordered-map(-inf)
    }
}

// ---------------- fused GRU: bf16 MFMA GEMMs + epilogue + masked col-max ----------------
__global__ __launch_bounds__(256, 2) void gru_main(
    const float* __restrict__ X,                 // co_embeddings [M,256]
    const float* __restrict__ H,                 // hidden_state  [M,256]
    const unsigned short* __restrict__ Wswz,     // swizzled bf16 weights
    const float* __restrict__ bih,
    const float* __restrict__ bhh,
    const int* __restrict__ maskbuf,
    float* __restrict__ hnew,                    // d_out + 256
    unsigned int* __restrict__ maxacc)
{
    __shared__ unsigned short Xs[64 * PITCH];
    __shared__ unsigned short Hs[64 * PITCH];

    const int tid  = threadIdx.x;
    const int lane = tid & 63;
    const int wave = tid >> 6;
    const int l32  = lane & 31;
    const int hi   = lane >> 5;
    const int wm   = wave & 1;                   // row half (0/1)
    const int wn   = wave >> 1;                  // col half (0/1)
    const int row0 = blockIdx.x * 64;

    // ---- stage X,H tiles f32 -> bf16 in LDS (coalesced float4 loads) ----
    #pragma unroll
    for (int i = 0; i < 16; ++i) {
        int idx = i * 256 + tid;                 // 0..4095
        int r   = idx >> 6;                      // row 0..63
        int c4  = idx & 63;                      // float4 col
        int gr  = row0 + r;
        float4 xv = make_float4(0.f, 0.f, 0.f, 0.f);
        float4 hv = make_float4(0.f, 0.f, 0.f, 0.f);
        if (gr < M_ROWS) {
            xv = reinterpret_cast<const float4*>(X)[gr * 64 + c4];
            hv = reinterpret_cast<const float4*>(H)[gr * 64 + c4];
        }
        uint2 xp, hp;
        xp.x = (unsigned)bf16_rne(xv.x) | ((unsigned)bf16_rne(xv.y) << 16);
        xp.y = (unsigned)bf16_rne(xv.z) | ((unsigned)bf16_rne(xv.w) << 16);
        hp.x = (unsigned)bf16_rne(hv.x) | ((unsigned)bf16_rne(hv.y) << 16);
        hp.y = (unsigned)bf16_rne(hv.z) | ((unsigned)bf16_rne(hv.w) << 16);
        *reinterpret_cast<uint2*>(&Xs[r * PITCH + c4 * 4]) = xp;
        *reinterpret_cast<uint2*>(&Hs[r * PITCH + c4 * 4]) = hp;
    }
    __syncthreads();

    // A-frag base: A[m = wm*32 + l32][k = kc*16 + hi*8 + j]
    const unsigned short* xa_base = &Xs[(wm * 32 + l32) * PITCH + hi * 8];
    const unsigned short* ha_base = &Hs[(wm * 32 + l32) * PITCH + hi * 8];

    for (int jt = 0; jt < 4; ++jt) {
        const int g  = jt * 2 + wn;              // 32-column group 0..7
        const int jj = g * 32 + l32;             // hidden-unit column 0..255

        // swizzled weight stream for this wave: chunk = wg[(kc*6+s)*64]
        const short8* wg = reinterpret_cast<const short8*>(Wswz) + (size_t)g * 6144 + lane;

        float16v acc[6];
        #pragma unroll
        for (int s = 0; s < 6; ++s)
            #pragma unroll
            for (int q = 0; q < 16; ++q) acc[s][q] = 0.0f;

        #pragma unroll
        for (int kc = 0; kc < 16; ++kc) {
            short8 ax = *reinterpret_cast<const short8*>(xa_base + kc * 16);
            short8 ah = *reinterpret_cast<const short8*>(ha_base + kc * 16);
            const short8* wk = wg + kc * 384;    // 6*64 chunks per kc
            short8 b0 = wk[0 * 64];
            short8 b1 = wk[1 * 64];
            short8 b2 = wk[2 * 64];
            short8 b3 = wk[3 * 64];
            short8 b4 = wk[4 * 64];
            short8 b5 = wk[5 * 64];
            acc[0] = __builtin_amdgcn_mfma_f32_32x32x16_bf16(ax, b0, acc[0], 0, 0, 0);
            acc[1] = __builtin_amdgcn_mfma_f32_32x32x16_bf16(ax, b1, acc[1], 0, 0, 0);
            acc[2] = __builtin_amdgcn_mfma_f32_32x32x16_bf16(ax, b2, acc[2], 0, 0, 0);
            acc[3] = __builtin_amdgcn_mfma_f32_32x32x16_bf16(ah, b3, acc[3], 0, 0, 0);
            acc[4] = __builtin_amdgcn_mfma_f32_32x32x16_bf16(ah, b4, acc[4], 0, 0, 0);
            acc[5] = __builtin_amdgcn_mfma_f32_32x32x16_bf16(ah, b5, acc[5], 0, 0, 0);
        }

        // ---- fused GRU epilogue: same (reg,lane) in all 6 accs == same (m, jj) ----
        const float bir = bih[jj], biz = bih[256 + jj], bin_ = bih[512 + jj];
        const float bhr = bhh[jj], bhz = bhh[256 + jj], bhn  = bhh[512 + jj];

        float colmax = -__builtin_inff();
        #pragma unroll
        for (int reg = 0; reg < 16; ++reg) {
            int rl = (reg & 3) + 8 * (reg >> 2) + 4 * hi;   // C/D row map (m74/m101)
            int m  = row0 + wm * 32 + rl;
            if (m < M_ROWS) {
                float gir = acc[0][reg] + bir;
                float giz = acc[1][reg] + biz;
                float gin = acc[2][reg] + bin_;
                float ghr = acc[3][reg] + bhr;
                float ghz = acc[4][reg] + bhz;
                float ghn = acc[5][reg] + bhn;
                float r = sigmoid_fast(gir + ghr);
                float z = sigmoid_fast(giz + ghz);
                float n = tanh_fast(gin + r * ghn);
                float hp = H[m * 256 + jj];                 // exact f32 h (L2-hot)
                float hv = (1.0f - z) * n + z * hp;
                int mk = maskbuf[m];
                __builtin_nontemporal_store(mk ? hv : 0.0f, &hnew[m * 256 + jj]);
                if (mk) colmax = fmaxf(colmax, hv);
            }
        }
        // lanes l and l+32 hold the same column -> one xor-32 reduce
        colmax = fmaxf(colmax, __shfl_xor(colmax, 32));
        if (hi == 0) {
            unsigned b = __builtin_bit_cast(unsigned, colmax);
            unsigned u = (b & 0x80000000u) ? ~b : (b | 0x80000000u);  // order-preserving map
            atomicMax(&maxacc[jj], u);
        }
        // Xs/Hs read-only after staging: no barrier between jt iterations
    }
}

// ---------------- finalize: unmap max, add time features ----------------
__global__ void finalize_kernel(const unsigned int* __restrict__ maxacc,
                                const float* __restrict__ interval,
                                const float* __restrict__ time_w,
                                const float* __restrict__ time_b,
                                float* __restrict__ out)
{
    int j = threadIdx.x;
    unsigned u = maxacc[j];
    unsigned b = (u & 0x80000000u) ? (u & 0x7FFFFFFFu) : ~u;
    float mx = __builtin_bit_cast(float, b);
    float inv = 1.0f / logf(interval[0] + 2.718281828459045f);
    out[j] = mx + tanhf(inv * time_w[j] + time_b[j]);
}

extern "C" void kernel_launch(void* const* d_in, const int* in_sizes, int n_in,
                              void* d_out, int out_size, void* d_ws, size_t ws_size,
                              hipStream_t stream) {
    const float* interval = (const float*)d_in[0];
    const float* co       = (const float*)d_in[2];
    const int*   divided  = (const int*)d_in[3];
    const float* hidden   = (const float*)d_in[7];
    const float* wih      = (const float*)d_in[8];
    const float* whh      = (const float*)d_in[9];
    const float* bih      = (const float*)d_in[10];
    const float* bhh      = (const float*)d_in[11];
    const float* time_w   = (const float*)d_in[12];
    const float* time_b   = (const float*)d_in[13];

    float* out  = (float*)d_out;     // [256] output, then [100000*256] h_new
    float* hnew = out + 256;

    // ws layout: swizzled bf16 weights (786432 B) | maxacc (1024 B) | mask (400000 B)
    unsigned short* wswz   = (unsigned short*)d_ws;
    unsigned int*   maxacc = (unsigned int*)((char*)d_ws + 786432);
    int*            maskbuf= (int*)((char*)d_ws + 786432 + 1024);

    int prep_elems  = NCHUNK + M_ROWS + 256;         // 149408
    int prep_blocks = (prep_elems + 255) / 256;      // 584

    prep_kernel<<<prep_blocks, 256, 0, stream>>>(wih, whh, divided, wswz, maxacc, maskbuf);

    int main_blocks = (M_ROWS + 63) / 64;            // 1563
    gru_main<<<main_blocks, 256, 0, stream>>>(co, hidden, wswz,
                                              bih, bhh, maskbuf, hnew, maxacc);

    finalize_kernel<<<1, 256, 0, stream>>>(maxacc, interval, time_w, time_b, out);
}

// Round 4
// 523.138 us; speedup vs baseline: 1.2924x; 1.2924x over previous
//
#include <hip/hip_runtime.h>
#include <hip/hip_bf16.h>
#include <math.h>

#define M_ROWS 100000
#define ROWS_PER_XCD 12500   // 8 * 12500 = 100000 exactly
#define NTILES 49            // ceil(12500/256)
#define NCHUNK 49152         // 8g * 16kc * 6s * 64lane  (16B chunks)

typedef __attribute__((ext_vector_type(8)))  short  short8;
typedef __attribute__((ext_vector_type(16))) float  float16v;

__device__ __forceinline__ unsigned short bf16_rne(float f) {
    unsigned u = __builtin_bit_cast(unsigned, f);
    u += 0x7FFFu + ((u >> 16) & 1u);
    return (unsigned short)(u >> 16);
}

__device__ __forceinline__ float sigmoid_fast(float x) {
    return 1.0f / (1.0f + __expf(-x));
}
__device__ __forceinline__ float tanh_fast(float x) {
    return 1.0f - 2.0f / (__expf(2.0f * x) + 1.0f);   // correct limits at +/-inf
}

__device__ __forceinline__ unsigned pack2_rn(float lo, float hi) {
    __hip_bfloat162 t = __float22bfloat162_rn(float2{lo, hi});
    unsigned u;
    __builtin_memcpy(&u, &t, 4);     // bit_cast rejects non-trivially-copyable
    return u;
}

// pack 8 f32 -> short8 bf16 (RNE)
__device__ __forceinline__ short8 pack_bf16x8(float4 a, float4 b) {
    union { short8 s; unsigned u[4]; } r;
    r.u[0] = pack2_rn(a.x, a.y);
    r.u[1] = pack2_rn(a.z, a.w);
    r.u[2] = pack2_rn(b.x, b.y);
    r.u[3] = pack2_rn(b.z, b.w);
    return r.s;
}

// ---------------------------------------------------------------------------
// prep: swizzle weights f32 -> bf16 into MFMA B-fragment chunk order
//   chunk c = ((g*16 + kc)*6 + s)*64 + lane   (16 B per chunk)
//   s = 0..2 ih r/z/n, 3..5 hh r/z/n; lane gives (col=lane&31, k-half=lane>>5)
// Also: row mask from `divided`, ordered-uint max accumulator init.
// ---------------------------------------------------------------------------
__global__ void prep_kernel(const float* __restrict__ wih,
                            const float* __restrict__ whh,
                            const int* __restrict__ divided,
                            unsigned short* __restrict__ wswz,
                            unsigned int* __restrict__ maxacc,
                            int* __restrict__ maskbuf)
{
    int idx = blockIdx.x * 256 + threadIdx.x;
    if (idx < NCHUNK) {
        int lane = idx & 63;
        int t    = idx >> 6;          // 0..767
        int s    = t % 6;
        int t2   = t / 6;             // 0..127
        int kc   = t2 & 15;
        int g    = t2 >> 4;           // 0..7
        int row  = (s % 3) * 256 + g * 32 + (lane & 31);
        int col  = kc * 16 + (lane >> 5) * 8;
        const float* src = (s < 3 ? wih : whh) + row * 256 + col;
        float4 a = reinterpret_cast<const float4*>(src)[0];
        float4 b = reinterpret_cast<const float4*>(src)[1];
        uint4 p;
        p.x = (unsigned)bf16_rne(a.x) | ((unsigned)bf16_rne(a.y) << 16);
        p.y = (unsigned)bf16_rne(a.z) | ((unsigned)bf16_rne(a.w) << 16);
        p.z = (unsigned)bf16_rne(b.x) | ((unsigned)bf16_rne(b.y) << 16);
        p.w = (unsigned)bf16_rne(b.z) | ((unsigned)bf16_rne(b.w) << 16);
        reinterpret_cast<uint4*>(wswz)[idx] = p;
    } else if (idx < NCHUNK + M_ROWS) {
        int m = idx - NCHUNK;
        maskbuf[m] = (divided[3 * m] > 0) | (divided[3 * m + 1] > 0) | (divided[3 * m + 2] > 0);
    } else if (idx < NCHUNK + M_ROWS + 256) {
        maxacc[idx - NCHUNK - M_ROWS] = 0u;    // below ordered-map(-inf)
    }
}

// ---------------------------------------------------------------------------
// main: persistent blocks, LDS-resident weight slice (96 KB, one column-group),
// stream row tiles. grid = 256 = (xcd row-range: blockIdx&7) x (g: slot&7) x
// (sub: slot>>3). 8 blocks sharing a row range sit on one XCD (assuming
// round-robin blockIdx->XCD) so X/H re-reads hit that XCD's L2.
// Hot loop: global f32 A-loads (double-buffered 2-kc groups) + ds_read + MFMA.
// No barriers after the one-time weight stage.
// ---------------------------------------------------------------------------
__global__ __launch_bounds__(512, 2) void gru_main(
    const float* __restrict__ X,                 // co_embeddings [M,256]
    const float* __restrict__ H,                 // hidden_state  [M,256]
    const unsigned short* __restrict__ Wswz,     // swizzled bf16 weights
    const float* __restrict__ bih,
    const float* __restrict__ bhh,
    const int* __restrict__ maskbuf,
    float* __restrict__ hnew,                    // d_out + 256
    unsigned int* __restrict__ maxacc)
{
    __shared__ unsigned short Wlds[NCHUNK];      // 49152 shorts = 96 KB (one g-slice)

    const int tid  = threadIdx.x;
    const int lane = tid & 63;
    const int wave = tid >> 6;                   // 0..7
    const int l32  = lane & 31;
    const int hi   = lane >> 5;

    const int b    = blockIdx.x;
    const int xcd  = b & 7;
    const int slot = b >> 3;
    const int g    = slot & 7;                   // column group (32 cols)
    const int sub  = slot >> 3;                  // 0..3 tile interleave
    const int base  = xcd * ROWS_PER_XCD;
    const int limit = base + ROWS_PER_XCD;

    // ---- one-time weight stage: contiguous 96 KB slice -> LDS ----
    {
        const uint4* ws = reinterpret_cast<const uint4*>(Wswz) + (size_t)g * 6144;
        uint4* wd = reinterpret_cast<uint4*>(Wlds);
        #pragma unroll
        for (int i = 0; i < 12; ++i) wd[i * 512 + tid] = ws[i * 512 + tid];
    }
    __syncthreads();

    const short8* wbase = reinterpret_cast<const short8*>(Wlds);
    const int jj = g * 32 + l32;
    const float bir = bih[jj], biz = bih[256 + jj], bin_ = bih[512 + jj];
    const float bhr = bhh[jj], bhz = bhh[256 + jj], bhn  = bhh[512 + jj];

    float colmax = -__builtin_inff();

    for (int t = sub; t < NTILES; t += 4) {
        const int wrow0 = base + t * 256 + wave * 32;  // this wave's 32 rows
        if (wrow0 >= limit) continue;                  // wave-uniform skip
        const int arow = min(wrow0 + l32, limit - 1);  // clamped A-frag row
        const float4* X4 = reinterpret_cast<const float4*>(X) + (size_t)arow * 64;
        const float4* H4 = reinterpret_cast<const float4*>(H) + (size_t)arow * 64;

        float16v acc[6];
        #pragma unroll
        for (int s = 0; s < 6; ++s)
            #pragma unroll
            for (int q = 0; q < 16; ++q) acc[s][q] = 0.0f;

        // double-buffered 2-kc groups: lane loads 32B per kc per matrix
        float4 xb[2][4], hb[2][4];
        #pragma unroll
        for (int c = 0; c < 2; ++c)
            #pragma unroll
            for (int f = 0; f < 2; ++f) {
                int fi = c * 4 + hi * 2 + f;           // kc = c
                xb[0][c * 2 + f] = X4[fi];
                hb[0][c * 2 + f] = H4[fi];
            }

        #pragma unroll
        for (int q = 0; q < 8; ++q) {
            const int cur = q & 1, nxt = cur ^ 1;
            if (q < 7) {
                #pragma unroll
                for (int c = 0; c < 2; ++c)
                    #pragma unroll
                    for (int f = 0; f < 2; ++f) {
                        int fi = (q * 2 + 2 + c) * 4 + hi * 2 + f;
                        xb[nxt][c * 2 + f] = X4[fi];
                        hb[nxt][c * 2 + f] = H4[fi];
                    }
            }
            short8 ax[2], ah[2];
            #pragma unroll
            for (int c = 0; c < 2; ++c) {
                ax[c] = pack_bf16x8(xb[cur][c * 2], xb[cur][c * 2 + 1]);
                ah[c] = pack_bf16x8(hb[cur][c * 2], hb[cur][c * 2 + 1]);
            }
            #pragma unroll
            for (int c = 0; c < 2; ++c) {
                const int kc = q * 2 + c;
                const short8* wk = wbase + (kc * 6) * 64 + lane;
                acc[0] = __builtin_amdgcn_mfma_f32_32x32x16_bf16(ax[c], wk[0],   acc[0], 0, 0, 0);
                acc[1] = __builtin_amdgcn_mfma_f32_32x32x16_bf16(ax[c], wk[64],  acc[1], 0, 0, 0);
                acc[2] = __builtin_amdgcn_mfma_f32_32x32x16_bf16(ax[c], wk[128], acc[2], 0, 0, 0);
                acc[3] = __builtin_amdgcn_mfma_f32_32x32x16_bf16(ah[c], wk[192], acc[3], 0, 0, 0);
                acc[4] = __builtin_amdgcn_mfma_f32_32x32x16_bf16(ah[c], wk[256], acc[4], 0, 0, 0);
                acc[5] = __builtin_amdgcn_mfma_f32_32x32x16_bf16(ah[c], wk[320], acc[5], 0, 0, 0);
            }
        }

        // ---- fused GRU epilogue: C/D map col=lane&31(=jj), row=(reg&3)+8*(reg>>2)+4*hi ----
        #pragma unroll
        for (int reg = 0; reg < 16; ++reg) {
            int rl = (reg & 3) + 8 * (reg >> 2) + 4 * hi;
            int m  = wrow0 + rl;
            if (m < limit) {
                float gir = acc[0][reg] + bir;
                float giz = acc[1][reg] + biz;
                float gin = acc[2][reg] + bin_;
                float ghr = acc[3][reg] + bhr;
                float ghz = acc[4][reg] + bhz;
                float ghn = acc[5][reg] + bhn;
                float r = sigmoid_fast(gir + ghr);
                float z = sigmoid_fast(giz + ghz);
                float n = tanh_fast(gin + r * ghn);
                float hp = H[(size_t)m * 256 + jj];        // exact f32 h (L2-hot)
                float hv = (1.0f - z) * n + z * hp;
                int mk = maskbuf[m];
                __builtin_nontemporal_store(mk ? hv : 0.0f, &hnew[(size_t)m * 256 + jj]);
                if (mk) colmax = fmaxf(colmax, hv);
            }
        }
    }

    // one atomic per column per block (lanes l and l+32 share jj)
    colmax = fmaxf(colmax, __shfl_xor(colmax, 32));
    if (hi == 0) {
        unsigned bb = __builtin_bit_cast(unsigned, colmax);
        unsigned u  = (bb & 0x80000000u) ? ~bb : (bb | 0x80000000u);
        atomicMax(&maxacc[jj], u);
    }
}

// ---------------- finalize: unmap max, add time features ----------------
__global__ void finalize_kernel(const unsigned int* __restrict__ maxacc,
                                const float* __restrict__ interval,
                                const float* __restrict__ time_w,
                                const float* __restrict__ time_b,
                                float* __restrict__ out)
{
    int j = threadIdx.x;
    unsigned u = maxacc[j];
    unsigned b = (u & 0x80000000u) ? (u & 0x7FFFFFFFu) : ~u;
    float mx = __builtin_bit_cast(float, b);
    float inv = 1.0f / logf(interval[0] + 2.718281828459045f);
    out[j] = mx + tanhf(inv * time_w[j] + time_b[j]);
}

extern "C" void kernel_launch(void* const* d_in, const int* in_sizes, int n_in,
                              void* d_out, int out_size, void* d_ws, size_t ws_size,
                              hipStream_t stream) {
    const float* interval = (const float*)d_in[0];
    const float* co       = (const float*)d_in[2];
    const int*   divided  = (const int*)d_in[3];
    const float* hidden   = (const float*)d_in[7];
    const float* wih      = (const float*)d_in[8];
    const float* whh      = (const float*)d_in[9];
    const float* bih      = (const float*)d_in[10];
    const float* bhh      = (const float*)d_in[11];
    const float* time_w   = (const float*)d_in[12];
    const float* time_b   = (const float*)d_in[13];

    float* out  = (float*)d_out;     // [256] output, then [100000*256] h_new
    float* hnew = out + 256;

    // ws layout: swizzled bf16 weights (786432 B) | maxacc (1024 B) | mask (400000 B)
    unsigned short* wswz   = (unsigned short*)d_ws;
    unsigned int*   maxacc = (unsigned int*)((char*)d_ws + 786432);
    int*            maskbuf= (int*)((char*)d_ws + 786432 + 1024);

    int prep_elems  = NCHUNK + M_ROWS + 256;         // 149408
    int prep_blocks = (prep_elems + 255) / 256;      // 584

    prep_kernel<<<prep_blocks, 256, 0, stream>>>(wih, whh, divided, wswz, maxacc, maskbuf);

    gru_main<<<256, 512, 0, stream>>>(co, hidden, wswz,
                                      bih, bhh, maskbuf, hnew, maxacc);

    finalize_kernel<<<1, 256, 0, stream>>>(maxacc, interval, time_w, time_b, out);
}